// Round 6
// baseline (12339.539 us; speedup 1.0000x reference)
//
#include <hip/hip_runtime.h>

// LSTM: B=64, T=1024, D=512, H=512. Gate order i,f,g,o.
// Phase A: xW GEMM, b-major tiles (block = 1 t x 64 b x 64 cols), xw stored [t][col][b] f16, bias fused.
// Phase B: persistent scan, 16 WGs x 512 thr = 4 row-groups(16 rows) x 4 slices(128 units).
//   Wave v: 16 units x ALL 4 gates (fused gates in-register, 1 barrier/step).
//   Tag-in-data publish (f16 h | epoch<<16), triple-buffered, relaxed agent atomics,
//   double-buffered poll sweeps (detection ~RT/2).

#define B_  64
#define T_  1024
#define D_  512
#define H_  512
#define G4H 2048

typedef _Float16 half8 __attribute__((ext_vector_type(8)));
typedef _Float16 half4 __attribute__((ext_vector_type(4)));
typedef float    f32x4 __attribute__((ext_vector_type(4)));
typedef unsigned long long ull;

static __device__ __forceinline__ float sigm(float x) { return 1.f / (1.f + __expf(-x)); }
static __device__ __forceinline__ float tanh_(float x) {
    float xc = fminf(fmaxf(x, -15.f), 15.f);
    float e  = __expf(2.f * xc);
    return (e - 1.f) / (e + 1.f);
}

// ---------------- init: transpose-convert kernel -> WkT f16 [2048][512]
__global__ void init_kernel(const float* __restrict__ Wk, _Float16* __restrict__ WkT) {
    int idx = blockIdx.x * blockDim.x + threadIdx.x;
    int total = D_ * G4H;
    int stride = gridDim.x * blockDim.x;
    for (int i = idx; i < total; i += stride) {
        int k = i >> 11;
        int n = i & (G4H - 1);
        WkT[(size_t)n * D_ + k] = (_Float16)Wk[i];
    }
}

// ---------------- phase A: xw[t][col][b] = x[b][t][:] @ Wk[:][col] + bias[col], f16
// block = one t, 64 b-rows x 64 cols. 4 waves, wave w covers b 16w..16w+15.
__global__ __launch_bounds__(256) void gemm_xw(const float* __restrict__ x,
                                               const _Float16* __restrict__ WkT,
                                               const float* __restrict__ bias,
                                               _Float16* __restrict__ xw,
                                               int tbase) {
    __shared__ _Float16 As[64][40];   // [b][k]
    __shared__ _Float16 Bst[64][40];  // [col][k]
    const int tid  = threadIdx.x;
    const int lane = tid & 63;
    const int wave = tid >> 6;
    const int l15  = lane & 15;
    const int quad = lane >> 4;
    const int n0   = blockIdx.x * 64;
    const int t    = tbase + blockIdx.y;

    f32x4 acc[4];
#pragma unroll
    for (int i = 0; i < 4; ++i) acc[i] = (f32x4){0.f, 0.f, 0.f, 0.f};

    const int ai = tid >> 2, ac = tid & 3;   // A: b-row ai, 8 floats at ac*8
    const int bn = tid >> 2, bq = tid & 3;   // B: col bn, 8 f16 at bq*8

    for (int kb = 0; kb < 16; ++kb) {
        __syncthreads();
        const float* ap = x + ((size_t)ai * T_ + t) * D_ + kb * 32 + ac * 8;
        f32x4 av0 = *(const f32x4*)ap;
        f32x4 av1 = *(const f32x4*)(ap + 4);
        half8 ah = { (_Float16)av0.x, (_Float16)av0.y, (_Float16)av0.z, (_Float16)av0.w,
                     (_Float16)av1.x, (_Float16)av1.y, (_Float16)av1.z, (_Float16)av1.w };
        *(half8*)&As[ai][ac * 8] = ah;
        half8 bv = *(const half8*)(WkT + (size_t)(n0 + bn) * D_ + kb * 32 + bq * 8);
        *(half8*)&Bst[bn][bq * 8] = bv;
        __syncthreads();

        half8 afrag = *(const half8*)&As[16 * wave + l15][quad * 8];
#pragma unroll
        for (int nt = 0; nt < 4; ++nt) {
            half8 bfrag = *(const half8*)&Bst[nt * 16 + l15][quad * 8];
            acc[nt] = __builtin_amdgcn_mfma_f32_16x16x32_f16(afrag, bfrag, acc[nt], 0, 0, 0);
        }
    }
    // epilogue: C rows = b (quad*4+r), col = n0+nt*16+l15. Store 4 b-contig f16 (8B).
    const int trow = (int)blockIdx.y;   // t - tbase
#pragma unroll
    for (int nt = 0; nt < 4; ++nt) {
        int col = n0 + nt * 16 + l15;
        float bs = bias[col];
        half4 hv = { (_Float16)(acc[nt][0] + bs), (_Float16)(acc[nt][1] + bs),
                     (_Float16)(acc[nt][2] + bs), (_Float16)(acc[nt][3] + bs) };
        *(half4*)(xw + ((size_t)trow * G4H + col) * B_ + 16 * wave + quad * 4) = hv;
    }
}

// ---------------- phase B: persistent scan, fused gates, tag-in-data
// 16 WGs x 512 thr (8 waves). WG w: group g=w&3 (rows g*16..+15), slice s=w>>2 (units s*128..+127).
// Wave v (0..7): units ut=s*128+v*16 .. +15, ALL 4 gates. bfrag[4][16] = 256 VGPR.
// hbuf: 3 slots x [64][512] tagged dwords (lo16 = h f16, hi16 = step+1).
__global__ __launch_bounds__(512, 1) void lstm_scan(const _Float16* __restrict__ xw,  // [ct][2048][64]
                                                    const float* __restrict__ Wr,     // [512][2048]
                                                    unsigned* __restrict__ hbuf,
                                                    float* __restrict__ cio,
                                                    float* __restrict__ out,
                                                    int t0, int t1) {
    const int w    = blockIdx.x;
    const int g    = w & 3;
    const int s    = w >> 2;
    const int tid  = threadIdx.x;
    const int lane = tid & 63;
    const int wave = tid >> 6;
    const int l15  = lane & 15;
    const int quad = lane >> 4;
    const int ut   = s * 128 + wave * 16;
    const int unit = ut + l15;

    // B-frags: 4 gates x 16 ksteps. col = gate*512 + unit.
    half8 bfrag[4][16];
#pragma unroll
    for (int gate = 0; gate < 4; ++gate) {
        const int col = gate * H_ + unit;
#pragma unroll
        for (int kt = 0; kt < 16; ++kt) {
            half8 v;
#pragma unroll
            for (int j = 0; j < 8; ++j)
                v[j] = (_Float16)Wr[(size_t)(kt * 32 + quad * 8 + j) * G4H + col];
            bfrag[gate][kt] = v;
        }
    }

    // lane owns rows g*16+quad*4+{0..3}, one unit. c-state in registers.
    float c[4] = {0.f, 0.f, 0.f, 0.f};
    if (t0 != 0) {
#pragma unroll
        for (int r = 0; r < 4; ++r)
            c[r] = cio[(size_t)(g * 16 + quad * 4 + r) * H_ + unit];
    }

    __shared__ _Float16 hS[16][520];   // [row][unit], pad 8

    const size_t slotSz = (size_t)B_ * H_;   // dwords
    const ull MASK = 0xffff0000ffff0000ull;

    for (int t = t0; t < t1; ++t) {
        // xw prefetch: [tl][col][b], 4 rows contiguous -> one 8B load per gate
        const _Float16* xb = xw + (size_t)(t - t0) * G4H * B_;
        const int b0 = g * 16 + quad * 4;
        half4 xg[4];
#pragma unroll
        for (int gate = 0; gate < 4; ++gate)
            xg[gate] = *(const half4*)(xb + ((size_t)(gate * H_ + unit)) * B_ + b0);

        if (t > 0) {
            // double-buffered poll of the group slab (16 rows x 256 ull), 8 ull/thread
            const ull* src = (const ull*)(hbuf + (size_t)((t - 1) % 3) * slotSz)
                             + (size_t)g * 4096 + tid;
            const unsigned tgt = (unsigned)(t & 0xffff);
            const ull expect = ((ull)tgt << 16) | ((ull)tgt << 48);
            ull v0[8], v1[8];
#pragma unroll
            for (int k = 0; k < 8; ++k)
                v0[k] = __hip_atomic_load(src + (size_t)k * 512, __ATOMIC_RELAXED, __HIP_MEMORY_SCOPE_AGENT);
#pragma unroll
            for (int k = 0; k < 8; ++k)
                v1[k] = __hip_atomic_load(src + (size_t)k * 512, __ATOMIC_RELAXED, __HIP_MEMORY_SCOPE_AGENT);
            int guard = 0;
            while (true) {
                ull d = 0;
#pragma unroll
                for (int k = 0; k < 8; ++k) d |= (v0[k] ^ expect) & MASK;
                if (d == 0) break;
#pragma unroll
                for (int k = 0; k < 8; ++k)
                    v0[k] = __hip_atomic_load(src + (size_t)k * 512, __ATOMIC_RELAXED, __HIP_MEMORY_SCOPE_AGENT);
                d = 0;
#pragma unroll
                for (int k = 0; k < 8; ++k) d |= (v1[k] ^ expect) & MASK;
                if (d == 0) {
#pragma unroll
                    for (int k = 0; k < 8; ++k) v0[k] = v1[k];
                    break;
                }
#pragma unroll
                for (int k = 0; k < 8; ++k)
                    v1[k] = __hip_atomic_load(src + (size_t)k * 512, __ATOMIC_RELAXED, __HIP_MEMORY_SCOPE_AGENT);
                if (++guard > (1 << 14)) break;   // bailout: visible failure, not a hang
            }
            // strip tags -> LDS
#pragma unroll
            for (int k = 0; k < 8; ++k) {
                int idx = k * 512 + tid;
                int row = idx >> 8, cu = idx & 255;
                unsigned p = (unsigned)(v0[k] & 0xffffu) | (((unsigned)(v0[k] >> 32)) << 16);
                *(unsigned*)&hS[row][2 * cu] = p;
            }
        }
        __syncthreads();   // the ONLY barrier per step

        f32x4 acc[4];
#pragma unroll
        for (int i = 0; i < 4; ++i) acc[i] = (f32x4){0.f, 0.f, 0.f, 0.f};
        if (t > 0) {
#pragma unroll
            for (int kt = 0; kt < 16; ++kt) {
                half8 af = *(const half8*)&hS[l15][kt * 32 + quad * 8];
                acc[0] = __builtin_amdgcn_mfma_f32_16x16x32_f16(af, bfrag[0][kt], acc[0], 0, 0, 0);
                acc[1] = __builtin_amdgcn_mfma_f32_16x16x32_f16(af, bfrag[1][kt], acc[1], 0, 0, 0);
                acc[2] = __builtin_amdgcn_mfma_f32_16x16x32_f16(af, bfrag[2][kt], acc[2], 0, 0, 0);
                acc[3] = __builtin_amdgcn_mfma_f32_16x16x32_f16(af, bfrag[3][kt], acc[3], 0, 0, 0);
            }
        }

        // gates fully in-register: lane has zi/zf/zg/zo for 4 rows x 1 unit
        const unsigned tagw = ((unsigned)((t + 1) & 0xffff)) << 16;
        unsigned dtag[4];
        float h[4];
#pragma unroll
        for (int r = 0; r < 4; ++r) {
            float zi = acc[0][r] + (float)xg[0][r];
            float zf = acc[1][r] + (float)xg[1][r];
            float zg = acc[2][r] + (float)xg[2][r];
            float zo = acc[3][r] + (float)xg[3][r];
            c[r] = sigm(zf) * c[r] + sigm(zi) * tanh_(zg);
            h[r] = sigm(zo) * tanh_(c[r]);
            dtag[r] = (unsigned)__builtin_bit_cast(unsigned short, (_Float16)h[r]) | tagw;
        }

        // pair adjacent units via shfl, 2 ull stores per lane (even: rows 0,1; odd: rows 2,3)
        unsigned ptag[4];
#pragma unroll
        for (int r = 0; r < 4; ++r) ptag[r] = __shfl_xor((int)dtag[r], 1);
        ull* slotw = (ull*)(hbuf + (size_t)(t % 3) * slotSz);
        const int pairb = (ut >> 1) + (l15 >> 1);
        const int r0 = (lane & 1) ? 2 : 0;
#pragma unroll
        for (int i = 0; i < 2; ++i) {
            int r = r0 + i;
            unsigned lo = (lane & 1) ? ptag[r] : dtag[r];
            unsigned hi = (lane & 1) ? dtag[r] : ptag[r];
            ull wv = (ull)lo | ((ull)hi << 32);
            __hip_atomic_store(slotw + (size_t)(g * 16 + quad * 4 + r) * 256 + pairb,
                               wv, __ATOMIC_RELAXED, __HIP_MEMORY_SCOPE_AGENT);
        }

        if (t == T_ - 1) {
#pragma unroll
            for (int r = 0; r < 4; ++r)
                out[(size_t)(g * 16 + quad * 4 + r) * H_ + unit] = h[r];
        }
    }
#pragma unroll
    for (int r = 0; r < 4; ++r)
        cio[(size_t)(g * 16 + quad * 4 + r) * H_ + unit] = c[r];
}

// ---------------- launch
extern "C" void kernel_launch(void* const* d_in, const int* in_sizes, int n_in,
                              void* d_out, int out_size, void* d_ws, size_t ws_size,
                              hipStream_t stream) {
    const float* x    = (const float*)d_in[0];
    const float* Wk   = (const float*)d_in[1];
    const float* Wr   = (const float*)d_in[2];
    const float* bias = (const float*)d_in[3];
    float* out = (float*)d_out;

    char* ws = (char*)d_ws;
    _Float16* WkT   = (_Float16*)(ws + 1024);                       // 2 MB
    unsigned* hbuf  = (unsigned*)(ws + 1024 + 2097152);             // 384 KB (3 slots)
    float*    cio   = (float*)  (ws + 1024 + 2097152 + 393216);     // 128 KB
    const size_t fixed = 1024 + 2097152 + 393216 + 131072;
    _Float16* xw    = (_Float16*)(ws + fixed);

    size_t avail = (ws_size > fixed) ? ws_size - fixed : 0;
    int ct = 0;
    const int cands[5] = {1024, 512, 256, 128, 64};
    for (int i = 0; i < 5; ++i) {
        if ((size_t)cands[i] * (size_t)(B_ * G4H * 2) <= avail) { ct = cands[i]; break; }
    }
    if (ct == 0) {
        hipMemsetAsync(d_out, 0, (size_t)out_size * 4, stream);
        return;
    }

    init_kernel<<<512, 256, 0, stream>>>(Wk, WkT);
    for (int t0 = 0; t0 < T_; t0 += ct) {
        gemm_xw<<<dim3(32, ct), 256, 0, stream>>>(x, WkT, bias, xw, t0);
        lstm_scan<<<16, 512, 0, stream>>>(xw, Wr, hbuf, cio, out, t0, t0 + ct);
    }
}